// Round 8
// baseline (694.274 us; speedup 1.0000x reference)
//
#include <hip/hip_runtime.h>
#include <hip/hip_fp16.h>
#include <math.h>

#define NNODE 50000
#define NEDGE 800000
#define FIN 128
#define EDIM 64
#define HC 256
#define NH 4
#define CC 64
#define SCAN_TILE 512

typedef _Float16 half8v __attribute__((ext_vector_type(8)));
typedef _Float16 half4v __attribute__((ext_vector_type(4)));
typedef float floatx4 __attribute__((ext_vector_type(4)));

// ---------------- fused setup: zero counts, cast W1/W2, we tables ----------------
// blocks [0,196): zero counts; [196,324): wt1; [324,580): wt2; [580,582): we1/we2
__global__ __launch_bounds__(256) void k_prep(int* counts,
                                              const float* __restrict__ W1, _Float16* wt1,
                                              const float* __restrict__ W2, _Float16* wt2,
                                              const float* __restrict__ eW1, const float* __restrict__ ae1, float* we1,
                                              const float* __restrict__ eW2, const float* __restrict__ ae2, float* we2) {
    int b = blockIdx.x, t = threadIdx.x;
    if (b < 196) {
        int i = b * 256 + t;
        if (i < NNODE) counts[i] = 0;
    } else if (b < 324) {
        int idx = (b - 196) * 256 + t;          // 32768 = 256n x 128k
        int n = idx >> 7, k = idx & 127;
        wt1[n * FIN + k] = (_Float16)W1[(size_t)k * HC + n];
    } else if (b < 580) {
        int idx = (b - 324) * 256 + t;          // 65536 = 256n x 256k
        int n = idx >> 8, k = idx & 255;
        wt2[n * HC + k] = (_Float16)W2[(size_t)k * HC + n];
    } else {
        int idx = (b - 580) * 256 + t;          // 512: [0,256)->layer1, [256,512)->layer2
        const float* eW = idx < 256 ? eW1 : eW2;
        const float* ae = idx < 256 ? ae1 : ae2;
        float* we = idx < 256 ? we1 : we2;
        int q = idx & 255;
        int d = q >> 2, hh = q & 3;
        float s = 0.f;
        for (int c = 0; c < 64; c++) s += eW[d * HC + hh * 64 + c] * ae[hh * 64 + c];
        we[d * 4 + hh] = s;
    }
}

// ---------------- count + rank (rank = arrival order within dst bucket) ----------------
__global__ void k_count(const int* __restrict__ dst, int* counts, int* __restrict__ rank, int E) {
    int e = blockIdx.x * 256 + threadIdx.x;
    if (e < E) rank[e] = atomicAdd(&counts[dst[e]], 1);
}

__global__ void k_scan1(const int* __restrict__ counts, int* offs, int* tilesums, int N) {
    __shared__ int s[SCAN_TILE];
    int t = threadIdx.x;
    int i = blockIdx.x * SCAN_TILE + t;
    int v = (i < N) ? counts[i] : 0;
    s[t] = v;
    for (int off = 1; off < SCAN_TILE; off <<= 1) {
        __syncthreads();
        int x = (t >= off) ? s[t - off] : 0;
        __syncthreads();
        s[t] += x;
    }
    __syncthreads();
    if (i < N) offs[i] = s[t] - v;  // exclusive within tile
    if (t == SCAN_TILE - 1) tilesums[blockIdx.x] = s[t];
}

// scan3 with fused tile-prefix: each block sums tilesums[0..b) from LDS
__global__ void k_scan3(int* offs, const int* __restrict__ tilesums, int nt, int N, int E) {
    __shared__ int sT[128];
    int t = threadIdx.x;
    if (t < 128) sT[t] = (t < nt) ? tilesums[t] : 0;
    __syncthreads();
    int b = blockIdx.x;
    int pre = 0;
    for (int i = 0; i < b; i++) pre += sT[i];   // uniform LDS broadcast loop
    int i = b * SCAN_TILE + t;
    if (i < N) offs[i] += pre;
    if (b == 0 && t == 0) offs[N] = E;
}

__device__ inline float4 h4_to_f4(uint2 r) {
    float2 fa = __half22float2(*(__half2*)&r.x);
    float2 fb = __half22float2(*(__half2*)&r.y);
    return make_float4(fa.x, fa.y, fb.x, fb.y);
}

__device__ inline float sel_h(float4 v, int head) {
    return head == 0 ? v.x : head == 1 ? v.y : head == 2 ? v.z : v.w;
}

// ---------------- fused CSR-fill + edge logits (single pass over edges) ----------------
// Edge-ordered: src/dst/rank and the 256B ef row are read SEQUENTIALLY. The full
// row is staged into a 16x float4 register array BEFORE any compute so all 16
// loads are in flight at once (VGPR-funded ILP; VGPR=32 round-7 proved the
// compiler otherwise serializes ~2-deep and the kernel goes latency-bound).
__global__ __launch_bounds__(256) void k_edge(const int* __restrict__ src,
                                              const int* __restrict__ dst,
                                              const int* __restrict__ rank,
                                              const int* __restrict__ offs,
                                              const float* __restrict__ ef,
                                              const float* __restrict__ we1,
                                              const float* __restrict__ we2,
                                              int* __restrict__ srcs,
                                              float* __restrict__ elogc1,
                                              float* __restrict__ elogc2, int E) {
    __shared__ float sw1[256], sw2[256];   // [c*4+head]
    int t = threadIdx.x;
    sw1[t] = we1[t];
    sw2[t] = we2[t];
    __syncthreads();
    int e = blockIdx.x * 256 + t;
    if (e >= E) return;

    // issue the whole 256B row first -- 16 loads in flight
    const float4* row = (const float4*)(ef + (size_t)e * EDIM);
    float4 v[16];
#pragma unroll
    for (int c4 = 0; c4 < 16; c4++) v[c4] = row[c4];

    // overlap index chain with the row loads
    int pos = offs[dst[e]] + rank[e];
    srcs[pos] = src[e];

    float a10 = 0.f, a11 = 0.f, a12 = 0.f, a13 = 0.f;
    float a20 = 0.f, a21 = 0.f, a22 = 0.f, a23 = 0.f;
#pragma unroll
    for (int c4 = 0; c4 < 16; c4++) {
        const float* vp = (const float*)&v[c4];
#pragma unroll
        for (int k = 0; k < 4; k++) {
            float vv = vp[k];
            int c = c4 * 4 + k;
            float4 w1 = *(const float4*)&sw1[c << 2];
            float4 w2 = *(const float4*)&sw2[c << 2];
            a10 += vv * w1.x; a11 += vv * w1.y; a12 += vv * w1.z; a13 += vv * w1.w;
            a20 += vv * w2.x; a21 += vv * w2.y; a22 += vv * w2.z; a23 += vv * w2.w;
        }
    }
    ((float4*)elogc1)[pos] = make_float4(a10, a11, a12, a13);
    ((float4*)elogc2)[pos] = make_float4(a20, a21, a22, a23);
}

// ---------------- fp16 MFMA GEMM + fused avec epilogue ----------------
template <typename AT>
__global__ __launch_bounds__(256) void k_gemm_mfma(const AT* __restrict__ A,
                                                   const _Float16* __restrict__ Wt16,
                                                   _Float16* __restrict__ H16,
                                                   const float* __restrict__ att_s,
                                                   const float* __restrict__ att_d,
                                                   float* __restrict__ asrc,
                                                   float* __restrict__ adst,
                                                   int M, int K) {
    int wave = threadIdx.x >> 6, lane = threadIdx.x & 63;
    int quad = lane >> 4, l16 = lane & 15;
    int row = blockIdx.x * 64 + wave * 16 + l16;     // A-frag row (m = lane&15)
    bool rok = row < M;
    floatx4 acc[16];
#pragma unroll
    for (int i = 0; i < 16; i++) acc[i] = (floatx4)(0.0f);
    int nk = K >> 5;
    for (int kk = 0; kk < nk; kk++) {
        half8v a = {};
        if (rok) {
            if constexpr (sizeof(AT) == 2) {
                a = *(const half8v*)(A + (size_t)row * K + kk * 32 + quad * 8);
            } else {
                const float* ap = (const float*)A + (size_t)row * K + kk * 32 + quad * 8;
                float4 v0 = *(const float4*)ap;
                float4 v1 = *(const float4*)(ap + 4);
                a[0] = (_Float16)v0.x; a[1] = (_Float16)v0.y;
                a[2] = (_Float16)v0.z; a[3] = (_Float16)v0.w;
                a[4] = (_Float16)v1.x; a[5] = (_Float16)v1.y;
                a[6] = (_Float16)v1.z; a[7] = (_Float16)v1.w;
            }
        }
#pragma unroll
        for (int nt = 0; nt < 16; nt++) {
            half8v b = *(const half8v*)(Wt16 + (size_t)(nt * 16 + l16) * K + kk * 32 + quad * 8);
            acc[nt] = __builtin_amdgcn_mfma_f32_16x16x32_f16(a, b, acc[nt], 0, 0, 0);
        }
    }
    // lane holds rows quad*4+r (r=0..3), cols nt*16+l16; head of col = nt>>2
    float asl[16], adl[16];
#pragma unroll
    for (int nt = 0; nt < 16; nt++) {
        asl[nt] = att_s[nt * 16 + l16];
        adl[nt] = att_d[nt * 16 + l16];
    }
    int orow0 = blockIdx.x * 64 + wave * 16 + quad * 4;
#pragma unroll
    for (int r = 0; r < 4; r++) {
        int orow = orow0 + r;
        float4 vs4, vd4;
        float* vsp = (float*)&vs4;
        float* vdp = (float*)&vd4;
#pragma unroll
        for (int hh = 0; hh < 4; hh++) {
            float vs = 0.f, vd = 0.f;
#pragma unroll
            for (int q = 0; q < 4; q++) {
                int nt = hh * 4 + q;
                float hv = acc[nt][r];
                vs += hv * asl[nt];
                vd += hv * adl[nt];
            }
            vs += __shfl_xor(vs, 1, 64); vd += __shfl_xor(vd, 1, 64);
            vs += __shfl_xor(vs, 2, 64); vd += __shfl_xor(vd, 2, 64);
            vs += __shfl_xor(vs, 4, 64); vd += __shfl_xor(vd, 4, 64);
            vs += __shfl_xor(vs, 8, 64); vd += __shfl_xor(vd, 8, 64);
            vsp[hh] = vs; vdp[hh] = vd;
        }
        if (l16 == 0 && orow < M) {
            ((float4*)asrc)[orow] = vs4;
            ((float4*)adst)[orow] = vd4;
        }
    }
#pragma unroll
    for (int r = 0; r < 4; r++) {
        int orow = orow0 + r;
        if (orow < M) {
#pragma unroll
            for (int nt = 0; nt < 16; nt++)
                H16[(size_t)orow * HC + nt * 16 + l16] = (_Float16)acc[nt][r];
        }
    }
}

// ---------------- fused attention + aggregation, wave-cooperative ----------------
// wave per node. Per 64-edge chunk:
//  Phase A (edge-parallel): lane j loads srcs/elog/asrc of edge j (COALESCED),
//    computes all-4-head weights with __expf, stores w4 to wave-private LDS.
//  Phase B (channel-parallel): per edge, readlane broadcasts src id to SGPR,
//    16 gathers kept in flight for MLP; weight via conflict-free LDS broadcast.
template <int LAYER>
__global__ __launch_bounds__(256) void k_aggr_fused(const _Float16* __restrict__ hb,
                                                    const float* __restrict__ elogc,
                                                    const float* __restrict__ asrc,
                                                    const float* __restrict__ adst,
                                                    const int* __restrict__ offs,
                                                    const int* __restrict__ srcs,
                                                    const float* __restrict__ bias,
                                                    _Float16* __restrict__ out16,
                                                    float* __restrict__ out32, int N) {
    __shared__ float sW[4][256];   // [wave][edge*4+head]
    int wave = threadIdx.x >> 6, lane = threadIdx.x & 63;
    int n = blockIdx.x * 4 + wave;
    if (n >= N) return;
    int head = lane >> 4;
    const uint2* hf = (const uint2*)hb;     // 4 halves per entry, 64 entries per row
    const float4* elc = (const float4*)elogc;
    const float4* asp = (const float4*)asrc;
    float* sWp = sW[wave];
    int beg = offs[n], end = offs[n + 1];

    float4 adn = ((const float4*)adst)[n];
    float adnh = sel_h(adn, head);

    float denom = 0.f;
    float sx = 0.f, sy = 0.f, sz = 0.f, sw = 0.f;  // raw elog sums (all heads)
    float ax = 0.f, ay = 0.f, az = 0.f, aw = 0.f;

    for (int i0 = beg; i0 < end; i0 += 64) {
        int m = end - i0; if (m > 64) m = 64;
        bool act = lane < m;
        int sj = 0;
        float4 el = make_float4(0.f, 0.f, 0.f, 0.f);
        float4 a4 = make_float4(0.f, 0.f, 0.f, 0.f);
        if (act) {
            uint idx = (uint)(i0 + lane);
            sj = srcs[idx];
            el = elc[idx];
            a4 = asp[(uint)sj];
        }
        sx += el.x; sy += el.y; sz += el.z; sw += el.w;
        float4 w4;
        float l;
        l = a4.x + adn.x + el.x; l = l > 0.f ? l : 0.2f * l; w4.x = act ? __expf(l) : 0.f;
        l = a4.y + adn.y + el.y; l = l > 0.f ? l : 0.2f * l; w4.y = act ? __expf(l) : 0.f;
        l = a4.z + adn.z + el.z; l = l > 0.f ? l : 0.2f * l; w4.z = act ? __expf(l) : 0.f;
        l = a4.w + adn.w + el.w; l = l > 0.f ? l : 0.2f * l; w4.w = act ? __expf(l) : 0.f;
        *(float4*)&sWp[lane << 2] = w4;
        __builtin_amdgcn_wave_barrier();   // wave-private LDS; DS pipe is in-order per wave

        int j = 0;
        for (; j + 16 <= m; j += 16) {
            uint2 r[16];
            float w[16];
#pragma unroll
            for (int k = 0; k < 16; k++) {
                int sk = __builtin_amdgcn_readlane(sj, j + k);   // SGPR broadcast
                w[k] = sWp[((j + k) << 2) + head];
                r[k] = hf[(size_t)((uint)sk * 64u) + lane];
            }
#pragma unroll
            for (int k = 0; k < 16; k++) {
                float4 h4 = h4_to_f4(r[k]);
                denom += w[k];
                ax += w[k] * h4.x; ay += w[k] * h4.y;
                az += w[k] * h4.z; aw += w[k] * h4.w;
            }
        }
        for (; j + 8 <= m; j += 8) {
            uint2 r[8];
            float w[8];
#pragma unroll
            for (int k = 0; k < 8; k++) {
                int sk = __builtin_amdgcn_readlane(sj, j + k);
                w[k] = sWp[((j + k) << 2) + head];
                r[k] = hf[(size_t)((uint)sk * 64u) + lane];
            }
#pragma unroll
            for (int k = 0; k < 8; k++) {
                float4 h4 = h4_to_f4(r[k]);
                denom += w[k];
                ax += w[k] * h4.x; ay += w[k] * h4.y;
                az += w[k] * h4.z; aw += w[k] * h4.w;
            }
        }
        for (; j < m; j++) {
            int sk = __builtin_amdgcn_readlane(sj, j);
            float wk = sWp[(j << 2) + head];
            uint2 rk = hf[(size_t)((uint)sk * 64u) + lane];
            float4 h4 = h4_to_f4(rk);
            denom += wk;
            ax += wk * h4.x; ay += wk * h4.y;
            az += wk * h4.z; aw += wk * h4.w;
        }
        __builtin_amdgcn_wave_barrier();   // before next chunk overwrites sW
    }

    // all-head elog totals (butterfly over 64 lanes), then pick own head
#pragma unroll
    for (int msk = 32; msk >= 1; msk >>= 1) {
        sx += __shfl_xor(sx, msk, 64);
        sy += __shfl_xor(sy, msk, 64);
        sz += __shfl_xor(sz, msk, 64);
        sw += __shfl_xor(sw, msk, 64);
    }
    float selh = sel_h(make_float4(sx, sy, sz, sw), head);

    // self-loop: attr = mean of incoming elog
    float cnt = (float)(end - beg);
    if (cnt < 1.f) cnt = 1.f;
    float asnh = sel_h(asp[(uint)n], head);
    float ls = asnh + adnh + selh / cnt;
    ls = ls > 0.f ? ls : 0.2f * ls;
    float ws = __expf(ls);
    denom += ws;
    float4 hn = h4_to_f4(hf[(size_t)n * 64 + lane]);
    ax += ws * hn.x; ay += ws * hn.y; az += ws * hn.z; aw += ws * hn.w;

    float inv = 1.0f / (denom + 1e-16f);
    ax *= inv; ay *= inv; az *= inv; aw *= inv;

    if (LAYER == 1) {
        float4 bv = ((const float4*)bias)[lane];
        half4v o;
        float v;
        v = ax + bv.x; o[0] = (_Float16)(v > 0.f ? v : __expf(v) - 1.0f);
        v = ay + bv.y; o[1] = (_Float16)(v > 0.f ? v : __expf(v) - 1.0f);
        v = az + bv.z; o[2] = (_Float16)(v > 0.f ? v : __expf(v) - 1.0f);
        v = aw + bv.w; o[3] = (_Float16)(v > 0.f ? v : __expf(v) - 1.0f);
        ((half4v*)(out16 + (size_t)n * HC))[lane] = o;
    } else {
        // mean over heads: reduce lanes {l, l^16, l^32, l^48}
        ax += __shfl_xor(ax, 16, 64); ax += __shfl_xor(ax, 32, 64);
        ay += __shfl_xor(ay, 16, 64); ay += __shfl_xor(ay, 32, 64);
        az += __shfl_xor(az, 16, 64); az += __shfl_xor(az, 32, 64);
        aw += __shfl_xor(aw, 16, 64); aw += __shfl_xor(aw, 32, 64);
        if (lane < 16) {
            float4 bv = ((const float4*)bias)[lane];
            float4 o;
            o.x = 0.25f * ax + bv.x;
            o.y = 0.25f * ay + bv.y;
            o.z = 0.25f * az + bv.z;
            o.w = 0.25f * aw + bv.w;
            ((float4*)(out32 + (size_t)n * CC))[lane] = o;
        }
    }
}

extern "C" void kernel_launch(void* const* d_in, const int* in_sizes, int n_in,
                              void* d_out, int out_size, void* d_ws, size_t ws_size,
                              hipStream_t stream) {
    const float* x   = (const float*)d_in[0];
    const float* ef  = (const float*)d_in[1];
    const int*   ei  = (const int*)d_in[2];
    const float* W1  = (const float*)d_in[3];
    const float* as1 = (const float*)d_in[4];
    const float* ad1 = (const float*)d_in[5];
    const float* ae1 = (const float*)d_in[6];
    const float* b1  = (const float*)d_in[7];
    const float* eW1 = (const float*)d_in[8];
    const float* W2  = (const float*)d_in[9];
    const float* as2 = (const float*)d_in[10];
    const float* ad2 = (const float*)d_in[11];
    const float* ae2 = (const float*)d_in[12];
    const float* b2  = (const float*)d_in[13];
    const float* eW2 = (const float*)d_in[14];
    float* out = (float*)d_out;
    const int* srcp = ei;
    const int* dstp = ei + NEDGE;

    char* w = (char*)d_ws;
    auto alloc = [&](size_t bytes) -> char* {
        char* r = w;
        w += (bytes + 255) / 256 * 256;
        return r;
    };
    _Float16* hb16  = (_Float16*)alloc((size_t)NNODE * HC * 2);   // h (fp16, both layers)
    _Float16* x216  = (_Float16*)alloc((size_t)NNODE * HC * 2);   // layer-2 GEMM input
    _Float16* wt1   = (_Float16*)alloc((size_t)HC * FIN * 2);     // W1^T fp16
    _Float16* wt2   = (_Float16*)alloc((size_t)HC * HC * 2);      // W2^T fp16
    float* elogc1 = (float*)alloc((size_t)NEDGE * 4 * 4);         // CSR-ordered
    float* elogc2 = (float*)alloc((size_t)NEDGE * 4 * 4);         // CSR-ordered
    float* asrc   = (float*)alloc((size_t)NNODE * 4 * 4);
    float* adst   = (float*)alloc((size_t)NNODE * 4 * 4);
    float* webuf1 = (float*)alloc(64 * 4 * 4);
    float* webuf2 = (float*)alloc(64 * 4 * 4);
    int* counts  = (int*)alloc((size_t)NNODE * 4);
    int* offs    = (int*)alloc((size_t)(NNODE + 1) * 4);
    int* tiles   = (int*)alloc(1024 * 4);
    int* rank    = (int*)alloc((size_t)NEDGE * 4);                // arrival rank within dst
    int* srcs    = (int*)alloc((size_t)NEDGE * 4);                // CSR-ordered src ids

    // fused setup (counts zeroing + weight transposes + we tables), one dispatch
    k_prep<<<582, 256, 0, stream>>>(counts, W1, wt1, W2, wt2,
                                    eW1, ae1, webuf1, eW2, ae2, webuf2);

    // CSR build (shared by both layers); rank recorded during count
    k_count<<<(NEDGE + 255) / 256, 256, 0, stream>>>(dstp, counts, rank, NEDGE);
    int nt = (NNODE + SCAN_TILE - 1) / SCAN_TILE;
    k_scan1<<<nt, SCAN_TILE, 0, stream>>>(counts, offs, tiles, NNODE);
    k_scan3<<<nt, SCAN_TILE, 0, stream>>>(offs, tiles, nt, NNODE, NEDGE);

    // fused CSR-fill + edge logits: ONE pass over edges, sequential ef reads
    k_edge<<<(NEDGE + 255) / 256, 256, 0, stream>>>(srcp, dstp, rank, offs, ef,
                                                    webuf1, webuf2, srcs, elogc1, elogc2, NEDGE);

    // ---- layer 1 ----
    k_gemm_mfma<float><<<(NNODE + 63) / 64, 256, 0, stream>>>(x, wt1, hb16, as1, ad1, asrc, adst, NNODE, FIN);
    k_aggr_fused<1><<<(NNODE + 3) / 4, 256, 0, stream>>>(hb16, elogc1, asrc, adst, offs, srcs, b1, x216, nullptr, NNODE);

    // ---- layer 2 ----
    k_gemm_mfma<_Float16><<<(NNODE + 63) / 64, 256, 0, stream>>>(x216, wt2, hb16, as2, ad2, asrc, adst, NNODE, HC);
    k_aggr_fused<2><<<(NNODE + 3) / 4, 256, 0, stream>>>(hb16, elogc2, asrc, adst, offs, srcs, b2, nullptr, out, NNODE);
}

// Round 9
// 667.234 us; speedup vs baseline: 1.0405x; 1.0405x over previous
//
#include <hip/hip_runtime.h>
#include <hip/hip_fp16.h>
#include <math.h>

#define NNODE 50000
#define NEDGE 800000
#define FIN 128
#define EDIM 64
#define HC 256
#define NH 4
#define CC 64
#define SCAN_TILE 512

typedef _Float16 half8v __attribute__((ext_vector_type(8)));
typedef _Float16 half4v __attribute__((ext_vector_type(4)));
typedef float floatx4 __attribute__((ext_vector_type(4)));

// ---------------- fused setup: zero counts, cast W1/W2, we tables ----------------
// blocks [0,196): zero counts; [196,324): wt1; [324,580): wt2; [580,582): we1/we2
__global__ __launch_bounds__(256) void k_prep(int* counts,
                                              const float* __restrict__ W1, _Float16* wt1,
                                              const float* __restrict__ W2, _Float16* wt2,
                                              const float* __restrict__ eW1, const float* __restrict__ ae1, float* we1,
                                              const float* __restrict__ eW2, const float* __restrict__ ae2, float* we2) {
    int b = blockIdx.x, t = threadIdx.x;
    if (b < 196) {
        int i = b * 256 + t;
        if (i < NNODE) counts[i] = 0;
    } else if (b < 324) {
        int idx = (b - 196) * 256 + t;          // 32768 = 256n x 128k
        int n = idx >> 7, k = idx & 127;
        wt1[n * FIN + k] = (_Float16)W1[(size_t)k * HC + n];
    } else if (b < 580) {
        int idx = (b - 324) * 256 + t;          // 65536 = 256n x 256k
        int n = idx >> 8, k = idx & 255;
        wt2[n * HC + k] = (_Float16)W2[(size_t)k * HC + n];
    } else {
        int idx = (b - 580) * 256 + t;          // 512: [0,256)->layer1, [256,512)->layer2
        const float* eW = idx < 256 ? eW1 : eW2;
        const float* ae = idx < 256 ? ae1 : ae2;
        float* we = idx < 256 ? we1 : we2;
        int q = idx & 255;
        int d = q >> 2, hh = q & 3;
        float s = 0.f;
        for (int c = 0; c < 64; c++) s += eW[d * HC + hh * 64 + c] * ae[hh * 64 + c];
        we[d * 4 + hh] = s;
    }
}

// ---------------- count + rank (rank = arrival order within dst bucket) ----------------
__global__ void k_count(const int* __restrict__ dst, int* counts, int* __restrict__ rank, int E) {
    int e = blockIdx.x * 256 + threadIdx.x;
    if (e < E) rank[e] = atomicAdd(&counts[dst[e]], 1);
}

__global__ void k_scan1(const int* __restrict__ counts, int* offs, int* tilesums, int N) {
    __shared__ int s[SCAN_TILE];
    int t = threadIdx.x;
    int i = blockIdx.x * SCAN_TILE + t;
    int v = (i < N) ? counts[i] : 0;
    s[t] = v;
    for (int off = 1; off < SCAN_TILE; off <<= 1) {
        __syncthreads();
        int x = (t >= off) ? s[t - off] : 0;
        __syncthreads();
        s[t] += x;
    }
    __syncthreads();
    if (i < N) offs[i] = s[t] - v;  // exclusive within tile
    if (t == SCAN_TILE - 1) tilesums[blockIdx.x] = s[t];
}

// scan3 with fused tile-prefix: each block sums tilesums[0..b) from LDS
__global__ void k_scan3(int* offs, const int* __restrict__ tilesums, int nt, int N, int E) {
    __shared__ int sT[128];
    int t = threadIdx.x;
    if (t < 128) sT[t] = (t < nt) ? tilesums[t] : 0;
    __syncthreads();
    int b = blockIdx.x;
    int pre = 0;
    for (int i = 0; i < b; i++) pre += sT[i];   // uniform LDS broadcast loop
    int i = b * SCAN_TILE + t;
    if (i < N) offs[i] += pre;
    if (b == 0 && t == 0) offs[N] = E;
}

__device__ inline float4 h4_to_f4(uint2 r) {
    float2 fa = __half22float2(*(__half2*)&r.x);
    float2 fb = __half22float2(*(__half2*)&r.y);
    return make_float4(fa.x, fa.y, fb.x, fb.y);
}

__device__ inline float sel_h(float4 v, int head) {
    return head == 0 ? v.x : head == 1 ? v.y : head == 2 ? v.z : v.w;
}

// ---------------- fused CSR-fill + edge logits, 4-lane-per-edge ----------------
// Lane group (g=lane>>2, r=lane&3): each lane loads 4 consecutive float4 of the
// row quarter r -> one wave load instruction covers a contiguous 4KB batch (32
// distinct lines in flight immediately; round-8 showed the 1-thread/row layout
// caps at ~40 lines/CU in flight = 2.3 TB/s latency-bound). Partial dots per
// lane, 2-step shfl_xor butterfly over r, lanes r=0/1/2 do the scattered writes.
__global__ __launch_bounds__(256) void k_edge(const int* __restrict__ src,
                                              const int* __restrict__ dst,
                                              const int* __restrict__ rank,
                                              const int* __restrict__ offs,
                                              const float* __restrict__ ef,
                                              const float* __restrict__ we1,
                                              const float* __restrict__ we2,
                                              int* __restrict__ srcs,
                                              float* __restrict__ elogc1,
                                              float* __restrict__ elogc2, int E) {
    __shared__ float sw1[256], sw2[256];   // [c*4+head]
    int t = threadIdx.x;
    sw1[t] = we1[t];
    sw2[t] = we2[t];
    __syncthreads();
    int lane = t & 63, wave = t >> 6;
    int g = lane >> 2, r = lane & 3;
    int e = blockIdx.x * 64 + wave * 16 + g;
    if (e >= E) return;

    // coalesced: 4 lanes cover the 256B row; wave covers 4KB contiguous
    const float4* row = (const float4*)(ef + (size_t)e * EDIM);
    float4 v0 = row[r * 4 + 0];
    float4 v1 = row[r * 4 + 1];
    float4 v2 = row[r * 4 + 2];
    float4 v3 = row[r * 4 + 3];

    int pos = offs[dst[e]] + rank[e];
    int sv = src[e];

    float a10 = 0.f, a11 = 0.f, a12 = 0.f, a13 = 0.f;
    float a20 = 0.f, a21 = 0.f, a22 = 0.f, a23 = 0.f;
    int c0 = r * 16;
    const float4* vv[4] = {&v0, &v1, &v2, &v3};
#pragma unroll
    for (int q = 0; q < 4; q++) {
        const float* vp = (const float*)vv[q];
#pragma unroll
        for (int k = 0; k < 4; k++) {
            float f = vp[k];
            int c = c0 + q * 4 + k;
            float4 w1 = *(const float4*)&sw1[c << 2];
            float4 w2 = *(const float4*)&sw2[c << 2];
            a10 += f * w1.x; a11 += f * w1.y; a12 += f * w1.z; a13 += f * w1.w;
            a20 += f * w2.x; a21 += f * w2.y; a22 += f * w2.z; a23 += f * w2.w;
        }
    }
    // butterfly over the 4-lane group (xor 1, 2 stay within group)
#pragma unroll
    for (int msk = 1; msk <= 2; msk <<= 1) {
        a10 += __shfl_xor(a10, msk, 64); a11 += __shfl_xor(a11, msk, 64);
        a12 += __shfl_xor(a12, msk, 64); a13 += __shfl_xor(a13, msk, 64);
        a20 += __shfl_xor(a20, msk, 64); a21 += __shfl_xor(a21, msk, 64);
        a22 += __shfl_xor(a22, msk, 64); a23 += __shfl_xor(a23, msk, 64);
    }
    if (r == 0) ((float4*)elogc1)[pos] = make_float4(a10, a11, a12, a13);
    else if (r == 1) ((float4*)elogc2)[pos] = make_float4(a20, a21, a22, a23);
    else if (r == 2) srcs[pos] = sv;
}

// ---------------- fp16 MFMA GEMM + fused avec epilogue ----------------
template <typename AT>
__global__ __launch_bounds__(256) void k_gemm_mfma(const AT* __restrict__ A,
                                                   const _Float16* __restrict__ Wt16,
                                                   _Float16* __restrict__ H16,
                                                   const float* __restrict__ att_s,
                                                   const float* __restrict__ att_d,
                                                   float* __restrict__ asrc,
                                                   float* __restrict__ adst,
                                                   int M, int K) {
    int wave = threadIdx.x >> 6, lane = threadIdx.x & 63;
    int quad = lane >> 4, l16 = lane & 15;
    int row = blockIdx.x * 64 + wave * 16 + l16;     // A-frag row (m = lane&15)
    bool rok = row < M;
    floatx4 acc[16];
#pragma unroll
    for (int i = 0; i < 16; i++) acc[i] = (floatx4)(0.0f);
    int nk = K >> 5;
    for (int kk = 0; kk < nk; kk++) {
        half8v a = {};
        if (rok) {
            if constexpr (sizeof(AT) == 2) {
                a = *(const half8v*)(A + (size_t)row * K + kk * 32 + quad * 8);
            } else {
                const float* ap = (const float*)A + (size_t)row * K + kk * 32 + quad * 8;
                float4 v0 = *(const float4*)ap;
                float4 v1 = *(const float4*)(ap + 4);
                a[0] = (_Float16)v0.x; a[1] = (_Float16)v0.y;
                a[2] = (_Float16)v0.z; a[3] = (_Float16)v0.w;
                a[4] = (_Float16)v1.x; a[5] = (_Float16)v1.y;
                a[6] = (_Float16)v1.z; a[7] = (_Float16)v1.w;
            }
        }
#pragma unroll
        for (int nt = 0; nt < 16; nt++) {
            half8v b = *(const half8v*)(Wt16 + (size_t)(nt * 16 + l16) * K + kk * 32 + quad * 8);
            acc[nt] = __builtin_amdgcn_mfma_f32_16x16x32_f16(a, b, acc[nt], 0, 0, 0);
        }
    }
    // lane holds rows quad*4+r (r=0..3), cols nt*16+l16; head of col = nt>>2
    float asl[16], adl[16];
#pragma unroll
    for (int nt = 0; nt < 16; nt++) {
        asl[nt] = att_s[nt * 16 + l16];
        adl[nt] = att_d[nt * 16 + l16];
    }
    int orow0 = blockIdx.x * 64 + wave * 16 + quad * 4;
#pragma unroll
    for (int r = 0; r < 4; r++) {
        int orow = orow0 + r;
        float4 vs4, vd4;
        float* vsp = (float*)&vs4;
        float* vdp = (float*)&vd4;
#pragma unroll
        for (int hh = 0; hh < 4; hh++) {
            float vs = 0.f, vd = 0.f;
#pragma unroll
            for (int q = 0; q < 4; q++) {
                int nt = hh * 4 + q;
                float hv = acc[nt][r];
                vs += hv * asl[nt];
                vd += hv * adl[nt];
            }
            vs += __shfl_xor(vs, 1, 64); vd += __shfl_xor(vd, 1, 64);
            vs += __shfl_xor(vs, 2, 64); vd += __shfl_xor(vd, 2, 64);
            vs += __shfl_xor(vs, 4, 64); vd += __shfl_xor(vd, 4, 64);
            vs += __shfl_xor(vs, 8, 64); vd += __shfl_xor(vd, 8, 64);
            vsp[hh] = vs; vdp[hh] = vd;
        }
        if (l16 == 0 && orow < M) {
            ((float4*)asrc)[orow] = vs4;
            ((float4*)adst)[orow] = vd4;
        }
    }
#pragma unroll
    for (int r = 0; r < 4; r++) {
        int orow = orow0 + r;
        if (orow < M) {
#pragma unroll
            for (int nt = 0; nt < 16; nt++)
                H16[(size_t)orow * HC + nt * 16 + l16] = (_Float16)acc[nt][r];
        }
    }
}

// ---------------- fused attention + aggregation, wave-cooperative ----------------
// wave per node. Per 64-edge chunk:
//  Phase A (edge-parallel): lane j loads srcs/elog/asrc of edge j (COALESCED),
//    computes all-4-head weights with __expf, stores w4 to wave-private LDS.
//  Phase B (channel-parallel): per edge, readlane broadcasts src id to SGPR,
//    16 gathers kept in flight for MLP; weight via conflict-free LDS broadcast.
template <int LAYER>
__global__ __launch_bounds__(256) void k_aggr_fused(const _Float16* __restrict__ hb,
                                                    const float* __restrict__ elogc,
                                                    const float* __restrict__ asrc,
                                                    const float* __restrict__ adst,
                                                    const int* __restrict__ offs,
                                                    const int* __restrict__ srcs,
                                                    const float* __restrict__ bias,
                                                    _Float16* __restrict__ out16,
                                                    float* __restrict__ out32, int N) {
    __shared__ float sW[4][256];   // [wave][edge*4+head]
    int wave = threadIdx.x >> 6, lane = threadIdx.x & 63;
    int n = blockIdx.x * 4 + wave;
    if (n >= N) return;
    int head = lane >> 4;
    const uint2* hf = (const uint2*)hb;     // 4 halves per entry, 64 entries per row
    const float4* elc = (const float4*)elogc;
    const float4* asp = (const float4*)asrc;
    float* sWp = sW[wave];
    int beg = offs[n], end = offs[n + 1];

    float4 adn = ((const float4*)adst)[n];
    float adnh = sel_h(adn, head);

    float denom = 0.f;
    float sx = 0.f, sy = 0.f, sz = 0.f, sw = 0.f;  // raw elog sums (all heads)
    float ax = 0.f, ay = 0.f, az = 0.f, aw = 0.f;

    for (int i0 = beg; i0 < end; i0 += 64) {
        int m = end - i0; if (m > 64) m = 64;
        bool act = lane < m;
        int sj = 0;
        float4 el = make_float4(0.f, 0.f, 0.f, 0.f);
        float4 a4 = make_float4(0.f, 0.f, 0.f, 0.f);
        if (act) {
            uint idx = (uint)(i0 + lane);
            sj = srcs[idx];
            el = elc[idx];
            a4 = asp[(uint)sj];
        }
        sx += el.x; sy += el.y; sz += el.z; sw += el.w;
        float4 w4;
        float l;
        l = a4.x + adn.x + el.x; l = l > 0.f ? l : 0.2f * l; w4.x = act ? __expf(l) : 0.f;
        l = a4.y + adn.y + el.y; l = l > 0.f ? l : 0.2f * l; w4.y = act ? __expf(l) : 0.f;
        l = a4.z + adn.z + el.z; l = l > 0.f ? l : 0.2f * l; w4.z = act ? __expf(l) : 0.f;
        l = a4.w + adn.w + el.w; l = l > 0.f ? l : 0.2f * l; w4.w = act ? __expf(l) : 0.f;
        *(float4*)&sWp[lane << 2] = w4;
        __builtin_amdgcn_wave_barrier();   // wave-private LDS; DS pipe is in-order per wave

        int j = 0;
        for (; j + 16 <= m; j += 16) {
            uint2 r[16];
            float w[16];
#pragma unroll
            for (int k = 0; k < 16; k++) {
                int sk = __builtin_amdgcn_readlane(sj, j + k);   // SGPR broadcast
                w[k] = sWp[((j + k) << 2) + head];
                r[k] = hf[(size_t)((uint)sk * 64u) + lane];
            }
#pragma unroll
            for (int k = 0; k < 16; k++) {
                float4 h4 = h4_to_f4(r[k]);
                denom += w[k];
                ax += w[k] * h4.x; ay += w[k] * h4.y;
                az += w[k] * h4.z; aw += w[k] * h4.w;
            }
        }
        for (; j + 8 <= m; j += 8) {
            uint2 r[8];
            float w[8];
#pragma unroll
            for (int k = 0; k < 8; k++) {
                int sk = __builtin_amdgcn_readlane(sj, j + k);
                w[k] = sWp[((j + k) << 2) + head];
                r[k] = hf[(size_t)((uint)sk * 64u) + lane];
            }
#pragma unroll
            for (int k = 0; k < 8; k++) {
                float4 h4 = h4_to_f4(r[k]);
                denom += w[k];
                ax += w[k] * h4.x; ay += w[k] * h4.y;
                az += w[k] * h4.z; aw += w[k] * h4.w;
            }
        }
        for (; j < m; j++) {
            int sk = __builtin_amdgcn_readlane(sj, j);
            float wk = sWp[(j << 2) + head];
            uint2 rk = hf[(size_t)((uint)sk * 64u) + lane];
            float4 h4 = h4_to_f4(rk);
            denom += wk;
            ax += wk * h4.x; ay += wk * h4.y;
            az += wk * h4.z; aw += wk * h4.w;
        }
        __builtin_amdgcn_wave_barrier();   // before next chunk overwrites sW
    }

    // all-head elog totals (butterfly over 64 lanes), then pick own head
#pragma unroll
    for (int msk = 32; msk >= 1; msk >>= 1) {
        sx += __shfl_xor(sx, msk, 64);
        sy += __shfl_xor(sy, msk, 64);
        sz += __shfl_xor(sz, msk, 64);
        sw += __shfl_xor(sw, msk, 64);
    }
    float selh = sel_h(make_float4(sx, sy, sz, sw), head);

    // self-loop: attr = mean of incoming elog
    float cnt = (float)(end - beg);
    if (cnt < 1.f) cnt = 1.f;
    float asnh = sel_h(asp[(uint)n], head);
    float ls = asnh + adnh + selh / cnt;
    ls = ls > 0.f ? ls : 0.2f * ls;
    float ws = __expf(ls);
    denom += ws;
    float4 hn = h4_to_f4(hf[(size_t)n * 64 + lane]);
    ax += ws * hn.x; ay += ws * hn.y; az += ws * hn.z; aw += ws * hn.w;

    float inv = 1.0f / (denom + 1e-16f);
    ax *= inv; ay *= inv; az *= inv; aw *= inv;

    if (LAYER == 1) {
        float4 bv = ((const float4*)bias)[lane];
        half4v o;
        float v;
        v = ax + bv.x; o[0] = (_Float16)(v > 0.f ? v : __expf(v) - 1.0f);
        v = ay + bv.y; o[1] = (_Float16)(v > 0.f ? v : __expf(v) - 1.0f);
        v = az + bv.z; o[2] = (_Float16)(v > 0.f ? v : __expf(v) - 1.0f);
        v = aw + bv.w; o[3] = (_Float16)(v > 0.f ? v : __expf(v) - 1.0f);
        ((half4v*)(out16 + (size_t)n * HC))[lane] = o;
    } else {
        // mean over heads: reduce lanes {l, l^16, l^32, l^48}
        ax += __shfl_xor(ax, 16, 64); ax += __shfl_xor(ax, 32, 64);
        ay += __shfl_xor(ay, 16, 64); ay += __shfl_xor(ay, 32, 64);
        az += __shfl_xor(az, 16, 64); az += __shfl_xor(az, 32, 64);
        aw += __shfl_xor(aw, 16, 64); aw += __shfl_xor(aw, 32, 64);
        if (lane < 16) {
            float4 bv = ((const float4*)bias)[lane];
            float4 o;
            o.x = 0.25f * ax + bv.x;
            o.y = 0.25f * ay + bv.y;
            o.z = 0.25f * az + bv.z;
            o.w = 0.25f * aw + bv.w;
            ((float4*)(out32 + (size_t)n * CC))[lane] = o;
        }
    }
}

extern "C" void kernel_launch(void* const* d_in, const int* in_sizes, int n_in,
                              void* d_out, int out_size, void* d_ws, size_t ws_size,
                              hipStream_t stream) {
    const float* x   = (const float*)d_in[0];
    const float* ef  = (const float*)d_in[1];
    const int*   ei  = (const int*)d_in[2];
    const float* W1  = (const float*)d_in[3];
    const float* as1 = (const float*)d_in[4];
    const float* ad1 = (const float*)d_in[5];
    const float* ae1 = (const float*)d_in[6];
    const float* b1  = (const float*)d_in[7];
    const float* eW1 = (const float*)d_in[8];
    const float* W2  = (const float*)d_in[9];
    const float* as2 = (const float*)d_in[10];
    const float* ad2 = (const float*)d_in[11];
    const float* ae2 = (const float*)d_in[12];
    const float* b2  = (const float*)d_in[13];
    const float* eW2 = (const float*)d_in[14];
    float* out = (float*)d_out;
    const int* srcp = ei;
    const int* dstp = ei + NEDGE;

    char* w = (char*)d_ws;
    auto alloc = [&](size_t bytes) -> char* {
        char* r = w;
        w += (bytes + 255) / 256 * 256;
        return r;
    };
    _Float16* hb16  = (_Float16*)alloc((size_t)NNODE * HC * 2);   // h (fp16, both layers)
    _Float16* x216  = (_Float16*)alloc((size_t)NNODE * HC * 2);   // layer-2 GEMM input
    _Float16* wt1   = (_Float16*)alloc((size_t)HC * FIN * 2);     // W1^T fp16
    _Float16* wt2   = (_Float16*)alloc((size_t)HC * HC * 2);      // W2^T fp16
    float* elogc1 = (float*)alloc((size_t)NEDGE * 4 * 4);         // CSR-ordered
    float* elogc2 = (float*)alloc((size_t)NEDGE * 4 * 4);         // CSR-ordered
    float* asrc   = (float*)alloc((size_t)NNODE * 4 * 4);
    float* adst   = (float*)alloc((size_t)NNODE * 4 * 4);
    float* webuf1 = (float*)alloc(64 * 4 * 4);
    float* webuf2 = (float*)alloc(64 * 4 * 4);
    int* counts  = (int*)alloc((size_t)NNODE * 4);
    int* offs    = (int*)alloc((size_t)(NNODE + 1) * 4);
    int* tiles   = (int*)alloc(1024 * 4);
    int* rank    = (int*)alloc((size_t)NEDGE * 4);                // arrival rank within dst
    int* srcs    = (int*)alloc((size_t)NEDGE * 4);                // CSR-ordered src ids

    // fused setup (counts zeroing + weight transposes + we tables), one dispatch
    k_prep<<<582, 256, 0, stream>>>(counts, W1, wt1, W2, wt2,
                                    eW1, ae1, webuf1, eW2, ae2, webuf2);

    // CSR build (shared by both layers); rank recorded during count
    k_count<<<(NEDGE + 255) / 256, 256, 0, stream>>>(dstp, counts, rank, NEDGE);
    int nt = (NNODE + SCAN_TILE - 1) / SCAN_TILE;
    k_scan1<<<nt, SCAN_TILE, 0, stream>>>(counts, offs, tiles, NNODE);
    k_scan3<<<nt, SCAN_TILE, 0, stream>>>(offs, tiles, nt, NNODE, NEDGE);

    // fused CSR-fill + edge logits: ONE pass over edges, 4-lane-per-edge coalesced
    k_edge<<<(NEDGE + 63) / 64, 256, 0, stream>>>(srcp, dstp, rank, offs, ef,
                                                  webuf1, webuf2, srcs, elogc1, elogc2, NEDGE);

    // ---- layer 1 ----
    k_gemm_mfma<float><<<(NNODE + 63) / 64, 256, 0, stream>>>(x, wt1, hb16, as1, ad1, asrc, adst, NNODE, FIN);
    k_aggr_fused<1><<<(NNODE + 3) / 4, 256, 0, stream>>>(hb16, elogc1, asrc, adst, offs, srcs, b1, x216, nullptr, NNODE);

    // ---- layer 2 ----
    k_gemm_mfma<_Float16><<<(NNODE + 63) / 64, 256, 0, stream>>>(x216, wt2, hb16, as2, ad2, asrc, adst, NNODE, HC);
    k_aggr_fused<2><<<(NNODE + 3) / 4, 256, 0, stream>>>(hb16, elogc2, asrc, adst, offs, srcs, b2, nullptr, out, NNODE);
}

// Round 12
// 665.689 us; speedup vs baseline: 1.0429x; 1.0023x over previous
//
#include <hip/hip_runtime.h>
#include <hip/hip_fp16.h>
#include <math.h>

#define NNODE 50000
#define NEDGE 800000
#define FIN 128
#define EDIM 64
#define HC 256
#define NH 4
#define CC 64
#define SCAN_TILE 512

typedef _Float16 half8v __attribute__((ext_vector_type(8)));
typedef _Float16 half4v __attribute__((ext_vector_type(4)));
typedef float floatx4 __attribute__((ext_vector_type(4)));

// ---------------- fused setup: zero counts, cast W1/W2, we tables ----------------
// blocks [0,196): zero counts; [196,324): wt1; [324,580): wt2; [580,582): we1/we2
__global__ __launch_bounds__(256) void k_prep(int* counts,
                                              const float* __restrict__ W1, _Float16* wt1,
                                              const float* __restrict__ W2, _Float16* wt2,
                                              const float* __restrict__ eW1, const float* __restrict__ ae1, float* we1,
                                              const float* __restrict__ eW2, const float* __restrict__ ae2, float* we2) {
    int b = blockIdx.x, t = threadIdx.x;
    if (b < 196) {
        int i = b * 256 + t;
        if (i < NNODE) counts[i] = 0;
    } else if (b < 324) {
        int idx = (b - 196) * 256 + t;          // 32768 = 256n x 128k
        int n = idx >> 7, k = idx & 127;
        wt1[n * FIN + k] = (_Float16)W1[(size_t)k * HC + n];
    } else if (b < 580) {
        int idx = (b - 324) * 256 + t;          // 65536 = 256n x 256k
        int n = idx >> 8, k = idx & 255;
        wt2[n * HC + k] = (_Float16)W2[(size_t)k * HC + n];
    } else {
        int idx = (b - 580) * 256 + t;          // 512: [0,256)->layer1, [256,512)->layer2
        const float* eW = idx < 256 ? eW1 : eW2;
        const float* ae = idx < 256 ? ae1 : ae2;
        float* we = idx < 256 ? we1 : we2;
        int q = idx & 255;
        int d = q >> 2, hh = q & 3;
        float s = 0.f;
        for (int c = 0; c < 64; c++) s += eW[d * HC + hh * 64 + c] * ae[hh * 64 + c];
        we[d * 4 + hh] = s;
    }
}

// ---------------- count + rank (rank = arrival order within dst bucket) ----------------
__global__ void k_count(const int* __restrict__ dst, int* counts, int* __restrict__ rank, int E) {
    int e = blockIdx.x * 256 + threadIdx.x;
    if (e < E) rank[e] = atomicAdd(&counts[dst[e]], 1);
}

__global__ void k_scan1(const int* __restrict__ counts, int* offs, int* tilesums, int N) {
    __shared__ int s[SCAN_TILE];
    int t = threadIdx.x;
    int i = blockIdx.x * SCAN_TILE + t;
    int v = (i < N) ? counts[i] : 0;
    s[t] = v;
    for (int off = 1; off < SCAN_TILE; off <<= 1) {
        __syncthreads();
        int x = (t >= off) ? s[t - off] : 0;
        __syncthreads();
        s[t] += x;
    }
    __syncthreads();
    if (i < N) offs[i] = s[t] - v;  // exclusive within tile
    if (t == SCAN_TILE - 1) tilesums[blockIdx.x] = s[t];
}

// scan3 with fused tile-prefix: each block sums tilesums[0..b) from LDS
__global__ void k_scan3(int* offs, const int* __restrict__ tilesums, int nt, int N, int E) {
    __shared__ int sT[128];
    int t = threadIdx.x;
    if (t < 128) sT[t] = (t < nt) ? tilesums[t] : 0;
    __syncthreads();
    int b = blockIdx.x;
    int pre = 0;
    for (int i = 0; i < b; i++) pre += sT[i];   // uniform LDS broadcast loop
    int i = b * SCAN_TILE + t;
    if (i < N) offs[i] += pre;
    if (b == 0 && t == 0) offs[N] = E;
}

__device__ inline float sel_h(float4 v, int head) {
    return head == 0 ? v.x : head == 1 ? v.y : head == 2 ? v.z : v.w;
}

// ---------------- fused CSR-fill + edge logits, 4-lane-per-edge ----------------
// Lane group (g=lane>>2, r=lane&3): each lane loads 4 consecutive float4 of the
// row quarter r -> one wave load instruction covers a contiguous span (MLP-funded;
// round-8/9 showed 1-thread/row caps at ~2.3 TB/s latency-bound, this got 694->667).
__global__ __launch_bounds__(256) void k_edge(const int* __restrict__ src,
                                              const int* __restrict__ dst,
                                              const int* __restrict__ rank,
                                              const int* __restrict__ offs,
                                              const float* __restrict__ ef,
                                              const float* __restrict__ we1,
                                              const float* __restrict__ we2,
                                              int* __restrict__ srcs,
                                              float* __restrict__ elogc1,
                                              float* __restrict__ elogc2, int E) {
    __shared__ float sw1[256], sw2[256];   // [c*4+head]
    int t = threadIdx.x;
    sw1[t] = we1[t];
    sw2[t] = we2[t];
    __syncthreads();
    int lane = t & 63, wave = t >> 6;
    int g = lane >> 2, r = lane & 3;
    int e = blockIdx.x * 64 + wave * 16 + g;
    if (e >= E) return;

    // coalesced: 4 lanes cover the 256B row; wave covers 4KB contiguous
    const float4* row = (const float4*)(ef + (size_t)e * EDIM);
    float4 v0 = row[r * 4 + 0];
    float4 v1 = row[r * 4 + 1];
    float4 v2 = row[r * 4 + 2];
    float4 v3 = row[r * 4 + 3];

    int pos = offs[dst[e]] + rank[e];
    int sv = src[e];

    float a10 = 0.f, a11 = 0.f, a12 = 0.f, a13 = 0.f;
    float a20 = 0.f, a21 = 0.f, a22 = 0.f, a23 = 0.f;
    int c0 = r * 16;
    const float4* vv[4] = {&v0, &v1, &v2, &v3};
#pragma unroll
    for (int q = 0; q < 4; q++) {
        const float* vp = (const float*)vv[q];
#pragma unroll
        for (int k = 0; k < 4; k++) {
            float f = vp[k];
            int c = c0 + q * 4 + k;
            float4 w1 = *(const float4*)&sw1[c << 2];
            float4 w2 = *(const float4*)&sw2[c << 2];
            a10 += f * w1.x; a11 += f * w1.y; a12 += f * w1.z; a13 += f * w1.w;
            a20 += f * w2.x; a21 += f * w2.y; a22 += f * w2.z; a23 += f * w2.w;
        }
    }
    // butterfly over the 4-lane group (xor 1, 2 stay within group)
#pragma unroll
    for (int msk = 1; msk <= 2; msk <<= 1) {
        a10 += __shfl_xor(a10, msk, 64); a11 += __shfl_xor(a11, msk, 64);
        a12 += __shfl_xor(a12, msk, 64); a13 += __shfl_xor(a13, msk, 64);
        a20 += __shfl_xor(a20, msk, 64); a21 += __shfl_xor(a21, msk, 64);
        a22 += __shfl_xor(a22, msk, 64); a23 += __shfl_xor(a23, msk, 64);
    }
    if (r == 0) ((float4*)elogc1)[pos] = make_float4(a10, a11, a12, a13);
    else if (r == 1) ((float4*)elogc2)[pos] = make_float4(a20, a21, a22, a23);
    else if (r == 2) srcs[pos] = sv;
}

// ---------------- fp16 MFMA GEMM + fused avec epilogue ----------------
template <typename AT>
__global__ __launch_bounds__(256) void k_gemm_mfma(const AT* __restrict__ A,
                                                   const _Float16* __restrict__ Wt16,
                                                   _Float16* __restrict__ H16,
                                                   const float* __restrict__ att_s,
                                                   const float* __restrict__ att_d,
                                                   float* __restrict__ asrc,
                                                   float* __restrict__ adst,
                                                   int M, int K) {
    int wave = threadIdx.x >> 6, lane = threadIdx.x & 63;
    int quad = lane >> 4, l16 = lane & 15;
    int row = blockIdx.x * 64 + wave * 16 + l16;     // A-frag row (m = lane&15)
    bool rok = row < M;
    floatx4 acc[16];
#pragma unroll
    for (int i = 0; i < 16; i++) acc[i] = (floatx4)(0.0f);
    int nk = K >> 5;
    for (int kk = 0; kk < nk; kk++) {
        half8v a = {};
        if (rok) {
            if constexpr (sizeof(AT) == 2) {
                a = *(const half8v*)(A + (size_t)row * K + kk * 32 + quad * 8);
            } else {
                const float* ap = (const float*)A + (size_t)row * K + kk * 32 + quad * 8;
                float4 v0 = *(const float4*)ap;
                float4 v1 = *(const float4*)(ap + 4);
                a[0] = (_Float16)v0.x; a[1] = (_Float16)v0.y;
                a[2] = (_Float16)v0.z; a[3] = (_Float16)v0.w;
                a[4] = (_Float16)v1.x; a[5] = (_Float16)v1.y;
                a[6] = (_Float16)v1.z; a[7] = (_Float16)v1.w;
            }
        }
#pragma unroll
        for (int nt = 0; nt < 16; nt++) {
            half8v b = *(const half8v*)(Wt16 + (size_t)(nt * 16 + l16) * K + kk * 32 + quad * 8);
            acc[nt] = __builtin_amdgcn_mfma_f32_16x16x32_f16(a, b, acc[nt], 0, 0, 0);
        }
    }
    // lane holds rows quad*4+r (r=0..3), cols nt*16+l16; head of col = nt>>2
    float asl[16], adl[16];
#pragma unroll
    for (int nt = 0; nt < 16; nt++) {
        asl[nt] = att_s[nt * 16 + l16];
        adl[nt] = att_d[nt * 16 + l16];
    }
    int orow0 = blockIdx.x * 64 + wave * 16 + quad * 4;
#pragma unroll
    for (int r = 0; r < 4; r++) {
        int orow = orow0 + r;
        float4 vs4, vd4;
        float* vsp = (float*)&vs4;
        float* vdp = (float*)&vd4;
#pragma unroll
        for (int hh = 0; hh < 4; hh++) {
            float vs = 0.f, vd = 0.f;
#pragma unroll
            for (int q = 0; q < 4; q++) {
                int nt = hh * 4 + q;
                float hv = acc[nt][r];
                vs += hv * asl[nt];
                vd += hv * adl[nt];
            }
            vs += __shfl_xor(vs, 1, 64); vd += __shfl_xor(vd, 1, 64);
            vs += __shfl_xor(vs, 2, 64); vd += __shfl_xor(vd, 2, 64);
            vs += __shfl_xor(vs, 4, 64); vd += __shfl_xor(vd, 4, 64);
            vs += __shfl_xor(vs, 8, 64); vd += __shfl_xor(vd, 8, 64);
            vsp[hh] = vs; vdp[hh] = vd;
        }
        if (l16 == 0 && orow < M) {
            ((float4*)asrc)[orow] = vs4;
            ((float4*)adst)[orow] = vd4;
        }
    }
#pragma unroll
    for (int r = 0; r < 4; r++) {
        int orow = orow0 + r;
        if (orow < M) {
#pragma unroll
            for (int nt = 0; nt < 16; nt++)
                H16[(size_t)orow * HC + nt * 16 + l16] = (_Float16)acc[nt][r];
        }
    }
}

// ---------------- fused attention + aggregation, 2 nodes per wave ----------------
// Half-wave per node (lanes 0-31 node A, 32-63 node B); each lane covers 8 fp16
// channels (uint4 = 16B, 32 lanes = full 512B h row). Every gather instruction
// fetches TWO rows (one per half) -> 32 rows in flight per wave at 16-deep batch,
// 2x the MLP of the 1-node/wave layout (round-9 lesson: these gathers are
// MLP-latency-bound). src broadcast via wave-private LDS (readlane is
// wave-uniform, can't differ per half).
template <int LAYER>
__global__ __launch_bounds__(256) void k_aggr_fused(const _Float16* __restrict__ hb,
                                                    const float* __restrict__ elogc,
                                                    const float* __restrict__ asrc,
                                                    const float* __restrict__ adst,
                                                    const int* __restrict__ offs,
                                                    const int* __restrict__ srcs,
                                                    const float* __restrict__ bias,
                                                    _Float16* __restrict__ out16,
                                                    float* __restrict__ out32, int N) {
    __shared__ float sW[4][2][32][4];   // [wave][half][edge][head]
    __shared__ int sS[4][2][32];        // [wave][half][edge] src ids
    int wave = threadIdx.x >> 6, lane = threadIdx.x & 63;
    int half = lane >> 5, hl = lane & 31;
    int n = blockIdx.x * 8 + wave * 2 + half;   // NNODE % 8 == 0: never divergent-exits
    if (n >= N) return;
    int head = hl >> 3;                          // channels hl*8..hl*8+7
    const uint4* hf4 = (const uint4*)hb;         // 8 halves per entry, 32 per row
    const float4* elc = (const float4*)elogc;
    const float4* asp = (const float4*)asrc;
    float* sWp = (float*)sW[wave][half];
    int* sSp = sS[wave][half];
    int beg = offs[n], end = offs[n + 1];

    float4 adn = ((const float4*)adst)[n];
    float adnh = sel_h(adn, head);

    float denom = 0.f;
    float sx = 0.f, sy = 0.f, sz = 0.f, sw_ = 0.f;  // raw elog sums (all heads)
    float acc[8] = {};

    for (int i0 = beg; i0 < end; i0 += 32) {
        int m = end - i0; if (m > 32) m = 32;
        bool act = hl < m;
        int sj = 0;
        float4 el = make_float4(0.f, 0.f, 0.f, 0.f);
        float4 a4 = make_float4(0.f, 0.f, 0.f, 0.f);
        if (act) {
            uint idx = (uint)(i0 + hl);
            sj = srcs[idx];
            el = elc[idx];
            a4 = asp[(uint)sj];
        }
        sx += el.x; sy += el.y; sz += el.z; sw_ += el.w;
        float4 w4;
        float l;
        l = a4.x + adn.x + el.x; l = l > 0.f ? l : 0.2f * l; w4.x = act ? __expf(l) : 0.f;
        l = a4.y + adn.y + el.y; l = l > 0.f ? l : 0.2f * l; w4.y = act ? __expf(l) : 0.f;
        l = a4.z + adn.z + el.z; l = l > 0.f ? l : 0.2f * l; w4.z = act ? __expf(l) : 0.f;
        l = a4.w + adn.w + el.w; l = l > 0.f ? l : 0.2f * l; w4.w = act ? __expf(l) : 0.f;
        *(float4*)&sWp[hl << 2] = w4;
        sSp[hl] = sj;
        __builtin_amdgcn_wave_barrier();   // wave-private LDS; DS pipe in-order per wave

        int j = 0;
        for (; j + 16 <= m; j += 16) {
            uint4 r[16];
            float w[16];
#pragma unroll
            for (int k = 0; k < 16; k++) {
                uint sk = (uint)sSp[j + k];        // broadcast per half
                w[k] = sWp[((j + k) << 2) + head];
                r[k] = hf4[(size_t)(sk * 32u + (uint)hl)];
            }
#pragma unroll
            for (int k = 0; k < 16; k++) {
                float w0 = w[k];
                denom += w0;
                float2 f0 = __half22float2(((const __half2*)&r[k])[0]);
                float2 f1 = __half22float2(((const __half2*)&r[k])[1]);
                float2 f2 = __half22float2(((const __half2*)&r[k])[2]);
                float2 f3 = __half22float2(((const __half2*)&r[k])[3]);
                acc[0] += w0 * f0.x; acc[1] += w0 * f0.y;
                acc[2] += w0 * f1.x; acc[3] += w0 * f1.y;
                acc[4] += w0 * f2.x; acc[5] += w0 * f2.y;
                acc[6] += w0 * f3.x; acc[7] += w0 * f3.y;
            }
        }
        for (; j + 8 <= m; j += 8) {
            uint4 r[8];
            float w[8];
#pragma unroll
            for (int k = 0; k < 8; k++) {
                uint sk = (uint)sSp[j + k];
                w[k] = sWp[((j + k) << 2) + head];
                r[k] = hf4[(size_t)(sk * 32u + (uint)hl)];
            }
#pragma unroll
            for (int k = 0; k < 8; k++) {
                float w0 = w[k];
                denom += w0;
                float2 f0 = __half22float2(((const __half2*)&r[k])[0]);
                float2 f1 = __half22float2(((const __half2*)&r[k])[1]);
                float2 f2 = __half22float2(((const __half2*)&r[k])[2]);
                float2 f3 = __half22float2(((const __half2*)&r[k])[3]);
                acc[0] += w0 * f0.x; acc[1] += w0 * f0.y;
                acc[2] += w0 * f1.x; acc[3] += w0 * f1.y;
                acc[4] += w0 * f2.x; acc[5] += w0 * f2.y;
                acc[6] += w0 * f3.x; acc[7] += w0 * f3.y;
            }
        }
        for (; j < m; j++) {
            uint sk = (uint)sSp[j];
            float w0 = sWp[(j << 2) + head];
            uint4 rk = hf4[(size_t)(sk * 32u + (uint)hl)];
            denom += w0;
            float2 f0 = __half22float2(((const __half2*)&rk)[0]);
            float2 f1 = __half22float2(((const __half2*)&rk)[1]);
            float2 f2 = __half22float2(((const __half2*)&rk)[2]);
            float2 f3 = __half22float2(((const __half2*)&rk)[3]);
            acc[0] += w0 * f0.x; acc[1] += w0 * f0.y;
            acc[2] += w0 * f1.x; acc[3] += w0 * f1.y;
            acc[4] += w0 * f2.x; acc[5] += w0 * f2.y;
            acc[6] += w0 * f3.x; acc[7] += w0 * f3.y;
        }
        __builtin_amdgcn_wave_barrier();   // before next chunk overwrites sW/sS
    }

    // all-head elog totals: butterfly within the 32-lane half
#pragma unroll
    for (int msk = 16; msk >= 1; msk >>= 1) {
        sx += __shfl_xor(sx, msk, 32);
        sy += __shfl_xor(sy, msk, 32);
        sz += __shfl_xor(sz, msk, 32);
        sw_ += __shfl_xor(sw_, msk, 32);
    }
    float selh = sel_h(make_float4(sx, sy, sz, sw_), head);

    // self-loop: attr = mean of incoming elog
    float cnt = (float)(end - beg);
    if (cnt < 1.f) cnt = 1.f;
    float asnh = sel_h(asp[(uint)n], head);
    float ls = asnh + adnh + selh / cnt;
    ls = ls > 0.f ? ls : 0.2f * ls;
    float ws = __expf(ls);
    denom += ws;
    uint4 hn = hf4[(size_t)((uint)n * 32u + (uint)hl)];
    {
        float2 f0 = __half22float2(((const __half2*)&hn)[0]);
        float2 f1 = __half22float2(((const __half2*)&hn)[1]);
        float2 f2 = __half22float2(((const __half2*)&hn)[2]);
        float2 f3 = __half22float2(((const __half2*)&hn)[3]);
        acc[0] += ws * f0.x; acc[1] += ws * f0.y;
        acc[2] += ws * f1.x; acc[3] += ws * f1.y;
        acc[4] += ws * f2.x; acc[5] += ws * f2.y;
        acc[6] += ws * f3.x; acc[7] += ws * f3.y;
    }

    float inv = 1.0f / (denom + 1e-16f);
#pragma unroll
    for (int c = 0; c < 8; c++) acc[c] *= inv;

    if (LAYER == 1) {
        const float4* bp = (const float4*)bias;
        float4 b0 = bp[hl * 2], b1 = bp[hl * 2 + 1];
        const float* b0p = (const float*)&b0;
        const float* b1p = (const float*)&b1;
        half8v o;
#pragma unroll
        for (int c = 0; c < 4; c++) {
            float v = acc[c] + b0p[c];
            o[c] = (_Float16)(v > 0.f ? v : __expf(v) - 1.0f);
        }
#pragma unroll
        for (int c = 0; c < 4; c++) {
            float v = acc[4 + c] + b1p[c];
            o[4 + c] = (_Float16)(v > 0.f ? v : __expf(v) - 1.0f);
        }
        ((half8v*)(out16 + (size_t)n * HC))[hl] = o;
    } else {
        // mean over heads: sum lanes {hl, hl^8, hl^16, hl^24} within the half
#pragma unroll
        for (int c = 0; c < 8; c++) {
            acc[c] += __shfl_xor(acc[c], 8, 32);
            acc[c] += __shfl_xor(acc[c], 16, 32);
        }
        if (hl < 8) {
            const float4* bp = (const float4*)bias;
            float4 b0 = bp[hl * 2], b1 = bp[hl * 2 + 1];
            float4 o0, o1;
            o0.x = 0.25f * acc[0] + b0.x; o0.y = 0.25f * acc[1] + b0.y;
            o0.z = 0.25f * acc[2] + b0.z; o0.w = 0.25f * acc[3] + b0.w;
            o1.x = 0.25f * acc[4] + b1.x; o1.y = 0.25f * acc[5] + b1.y;
            o1.z = 0.25f * acc[6] + b1.z; o1.w = 0.25f * acc[7] + b1.w;
            float4* op = (float4*)(out32 + (size_t)n * CC + hl * 8);
            op[0] = o0; op[1] = o1;
        }
    }
}

extern "C" void kernel_launch(void* const* d_in, const int* in_sizes, int n_in,
                              void* d_out, int out_size, void* d_ws, size_t ws_size,
                              hipStream_t stream) {
    const float* x   = (const float*)d_in[0];
    const float* ef  = (const float*)d_in[1];
    const int*   ei  = (const int*)d_in[2];
    const float* W1  = (const float*)d_in[3];
    const float* as1 = (const float*)d_in[4];
    const float* ad1 = (const float*)d_in[5];
    const float* ae1 = (const float*)d_in[6];
    const float* b1  = (const float*)d_in[7];
    const float* eW1 = (const float*)d_in[8];
    const float* W2  = (const float*)d_in[9];
    const float* as2 = (const float*)d_in[10];
    const float* ad2 = (const float*)d_in[11];
    const float* ae2 = (const float*)d_in[12];
    const float* b2  = (const float*)d_in[13];
    const float* eW2 = (const float*)d_in[14];
    float* out = (float*)d_out;
    const int* srcp = ei;
    const int* dstp = ei + NEDGE;

    char* w = (char*)d_ws;
    auto alloc = [&](size_t bytes) -> char* {
        char* r = w;
        w += (bytes + 255) / 256 * 256;
        return r;
    };
    _Float16* hb16  = (_Float16*)alloc((size_t)NNODE * HC * 2);   // h (fp16, both layers)
    _Float16* x216  = (_Float16*)alloc((size_t)NNODE * HC * 2);   // layer-2 GEMM input
    _Float16* wt1   = (_Float16*)alloc((size_t)HC * FIN * 2);     // W1^T fp16
    _Float16* wt2   = (_Float16*)alloc((size_t)HC * HC * 2);      // W2^T fp16
    float* elogc1 = (float*)alloc((size_t)NEDGE * 4 * 4);         // CSR-ordered
    float* elogc2 = (float*)alloc((size_t)NEDGE * 4 * 4);         // CSR-ordered
    float* asrc   = (float*)alloc((size_t)NNODE * 4 * 4);
    float* adst   = (float*)alloc((size_t)NNODE * 4 * 4);
    float* webuf1 = (float*)alloc(64 * 4 * 4);
    float* webuf2 = (float*)alloc(64 * 4 * 4);
    int* counts  = (int*)alloc((size_t)NNODE * 4);
    int* offs    = (int*)alloc((size_t)(NNODE + 1) * 4);
    int* tiles   = (int*)alloc(1024 * 4);
    int* rank    = (int*)alloc((size_t)NEDGE * 4);                // arrival rank within dst
    int* srcs    = (int*)alloc((size_t)NEDGE * 4);                // CSR-ordered src ids

    // fused setup (counts zeroing + weight transposes + we tables), one dispatch
    k_prep<<<582, 256, 0, stream>>>(counts, W1, wt1, W2, wt2,
                                    eW1, ae1, webuf1, eW2, ae2, webuf2);

    // CSR build (shared by both layers); rank recorded during count
    k_count<<<(NEDGE + 255) / 256, 256, 0, stream>>>(dstp, counts, rank, NEDGE);
    int nt = (NNODE + SCAN_TILE - 1) / SCAN_TILE;
    k_scan1<<<nt, SCAN_TILE, 0, stream>>>(counts, offs, tiles, NNODE);
    k_scan3<<<nt, SCAN_TILE, 0, stream>>>(offs, tiles, nt, NNODE, NEDGE);

    // fused CSR-fill + edge logits: ONE pass over edges, 4-lane-per-edge coalesced
    k_edge<<<(NEDGE + 63) / 64, 256, 0, stream>>>(srcp, dstp, rank, offs, ef,
                                                  webuf1, webuf2, srcs, elogc1, elogc2, NEDGE);

    // ---- layer 1 ----
    k_gemm_mfma<float><<<(NNODE + 63) / 64, 256, 0, stream>>>(x, wt1, hb16, as1, ad1, asrc, adst, NNODE, FIN);
    k_aggr_fused<1><<<(NNODE + 7) / 8, 256, 0, stream>>>(hb16, elogc1, asrc, adst, offs, srcs, b1, x216, nullptr, NNODE);

    // ---- layer 2 ----
    k_gemm_mfma<_Float16><<<(NNODE + 63) / 64, 256, 0, stream>>>(x216, wt2, hb16, as2, ad2, asrc, adst, NNODE, HC);
    k_aggr_fused<2><<<(NNODE + 7) / 8, 256, 0, stream>>>(hb16, elogc2, asrc, adst, offs, srcs, b2, nullptr, out, NNODE);
}